// Round 1
// baseline (354.134 us; speedup 1.0000x reference)
//
#include <hip/hip_runtime.h>
#include <hip/hip_bf16.h>
#include <cstdint>

#define NN 2000   // nodes
#define NB 32     // batch
#define DD 32     // d_in == d_out
#define HH 64     // hidden
#define EE 16     // env features
#define NP 24     // periods
#define MAXNZ 256 // per-row nnz capacity (mean ~100, sd ~10)

// ---------------- env = relu(env_features @ W_env + b_env) : [NN, HH] ----------------
__global__ __launch_bounds__(64) void k_env(const float* __restrict__ envf,
                                            const float* __restrict__ Wenv,
                                            const float* __restrict__ benv,
                                            float* __restrict__ env) {
    int n = blockIdx.x, h = threadIdx.x;
    float acc = benv[h];
#pragma unroll
    for (int e = 0; e < EE; ++e) acc = fmaf(envf[n * EE + e], Wenv[e * HH + h], acc);
    env[n * HH + h] = fmaxf(acc, 0.f);
}

// ------- support = x @ W ; residual = relu(x @ Wres + bres) : [NB*NN, DD] each -------
__global__ __launch_bounds__(256) void k_supp_res(const float* __restrict__ x,
                                                  const float* __restrict__ W,
                                                  const float* __restrict__ Wres,
                                                  const float* __restrict__ bres,
                                                  float* __restrict__ supp,
                                                  float* __restrict__ resd) {
    __shared__ float w[DD * DD], wr[DD * DD];
    for (int i = threadIdx.x; i < DD * DD; i += 256) { w[i] = W[i]; wr[i] = Wres[i]; }
    __syncthreads();
    int idx = blockIdx.x * 256 + threadIdx.x;
    if (idx >= NB * NN) return;
    float xv[DD];
    const float4* xr = (const float4*)(x + (size_t)idx * DD);
#pragma unroll
    for (int q = 0; q < DD / 4; ++q) {
        float4 v = xr[q];
        xv[4 * q] = v.x; xv[4 * q + 1] = v.y; xv[4 * q + 2] = v.z; xv[4 * q + 3] = v.w;
    }
    float sa[DD], ra[DD];
#pragma unroll
    for (int m = 0; m < DD; ++m) { sa[m] = 0.f; ra[m] = bres[m]; }
#pragma unroll
    for (int d = 0; d < DD; ++d) {
        float xd = xv[d];
#pragma unroll
        for (int m = 0; m < DD; ++m) {
            sa[m] = fmaf(xd, w[d * DD + m], sa[m]);
            ra[m] = fmaf(xd, wr[d * DD + m], ra[m]);
        }
    }
    float4* so = (float4*)(supp + (size_t)idx * DD);
    float4* ro = (float4*)(resd + (size_t)idx * DD);
#pragma unroll
    for (int q = 0; q < DD / 4; ++q) {
        so[q] = make_float4(sa[4 * q], sa[4 * q + 1], sa[4 * q + 2], sa[4 * q + 3]);
        ro[q] = make_float4(fmaxf(ra[4 * q], 0.f), fmaxf(ra[4 * q + 1], 0.f),
                            fmaxf(ra[4 * q + 2], 0.f), fmaxf(ra[4 * q + 3], 0.f));
    }
}

// ---------------- Tm = tgt_emb + env (broadcast over periods) : [NP, NN, HH] ----------------
__global__ __launch_bounds__(256) void k_tm(const float* __restrict__ tgt,
                                            const float* __restrict__ env,
                                            float* __restrict__ Tm) {
    int i = blockIdx.x * 256 + threadIdx.x;          // float4 index
    if (i >= NP * NN * HH / 4) return;
    int hq = i & (HH / 4 - 1);                       // 0..15
    int pk = i >> 4;                                 // p*NN + k
    int k = pk % NN;
    const float4* t4 = (const float4*)tgt;
    const float4* e4 = (const float4*)env;
    float4 tv = t4[i], ev = e4[k * (HH / 4) + hq];
    ((float4*)Tm)[i] = make_float4(tv.x + ev.x, tv.y + ev.y, tv.z + ev.z, tv.w + ev.w);
}

// ---------------- compact adj rows: kidx/kval lists + counts ----------------
__global__ __launch_bounds__(256) void k_sparse(const float* __restrict__ adj,
                                                int* __restrict__ kidx,
                                                float* __restrict__ kval,
                                                int* __restrict__ cnt) {
    __shared__ int c;
    if (threadIdx.x == 0) c = 0;
    __syncthreads();
    int n = blockIdx.x;
    for (int k = threadIdx.x; k < NN; k += 256) {
        float v = adj[(size_t)n * NN + k];
        if (v > 0.f) {
            int p = atomicAdd(&c, 1);
            if (p < MAXNZ) { kidx[n * MAXNZ + p] = k; kval[n * MAXNZ + p] = v; }
        }
    }
    __syncthreads();
    if (threadIdx.x == 0) cnt[n] = min(c, MAXNZ);
}

// ---------------- period -> batch lists ----------------
__global__ __launch_bounds__(64) void k_periods(const int* __restrict__ cyc,
                                                int* __restrict__ pcnt,
                                                int* __restrict__ plist) {
    __shared__ int c[NP];
    __shared__ int l[NP * NB];
    int t = threadIdx.x;
    if (t < NP) c[t] = 0;
    for (int i = t; i < NP * NB; i += 64) l[i] = 0;
    __syncthreads();
    if (t < NB) {
        int p = cyc[t] % NP; if (p < 0) p += NP;
        int s = atomicAdd(&c[p], 1);
        l[p * NB + s] = t;
    }
    __syncthreads();
    if (t < NP) pcnt[t] = c[t];
    for (int i = t; i < NP * NB; i += 64) plist[i] = l[i];
}

// ---------------- main: per (p, n): sparse A row -> conv -> epilogue ----------------
__global__ __launch_bounds__(256) void k_conv(const float* __restrict__ src,   // [NP,NN,HH]
                                              const float* __restrict__ Tm,    // [NP,NN,HH]
                                              const float* __restrict__ env,   // [NN,HH]
                                              const float* __restrict__ supp,  // [NB,NN,DD]
                                              const float* __restrict__ resd,  // [NB,NN,DD]
                                              const float* __restrict__ bias,  // [DD]
                                              const int* __restrict__ kidx,
                                              const float* __restrict__ kval,
                                              const int* __restrict__ cnt,
                                              const int* __restrict__ pcnt,
                                              const int* __restrict__ plist,
                                              float* __restrict__ out) {
    int bi = blockIdx.x;
    int p = bi / NN;
    int n = bi - p * NN;
    int nb = pcnt[p];
    if (nb == 0) return;                       // inactive period: nothing to do
    __shared__ float S[HH];
    __shared__ float avals[MAXNZ];
    __shared__ int kks[MAXNZ];
    __shared__ float part[256];
    int t = threadIdx.x;
    if (t < HH) S[t] = src[((size_t)p * NN + n) * HH + t] + env[n * HH + t];
    int c = cnt[n];
    __syncthreads();
    if (t < c) {                               // one thread per nonzero of row n
        int k = kidx[n * MAXNZ + t];
        const float4* tr = (const float4*)(Tm + ((size_t)p * NN + k) * HH);
        float acc = 0.f;
#pragma unroll
        for (int q = 0; q < HH / 4; ++q) {
            float4 tv = tr[q];
            acc = fmaf(tv.x, S[4 * q], acc);
            acc = fmaf(tv.y, S[4 * q + 1], acc);
            acc = fmaf(tv.z, S[4 * q + 2], acc);
            acc = fmaf(tv.w, S[4 * q + 3], acc);
        }
        avals[t] = fmaxf(acc, 0.f) * kval[n * MAXNZ + t];
        kks[t] = k;
    }
    __syncthreads();
    int m = t & 31, g = t >> 5;                // 8 j-groups x 32 outputs
    for (int ib = 0; ib < nb; ++ib) {
        int b = plist[p * NB + ib];
        const float* sb = supp + (size_t)b * NN * DD;
        float acc = 0.f;
        for (int j = g; j < c; j += 8)
            acc = fmaf(avals[j], sb[(size_t)kks[j] * DD + m], acc);
        part[t] = acc;
        __syncthreads();
        if (t < DD) {
            float s = bias[t];
#pragma unroll
            for (int gg = 0; gg < 8; ++gg) s += part[gg * 32 + t];
            size_t o = ((size_t)b * NN + n) * DD + t;
            out[o] = fmaxf(s + resd[o], 0.f);
        }
        __syncthreads();                       // part[] reused next batch
    }
}

extern "C" void kernel_launch(void* const* d_in, const int* in_sizes, int n_in,
                              void* d_out, int out_size, void* d_ws, size_t ws_size,
                              hipStream_t stream) {
    const float* x    = (const float*)d_in[0];
    const int*   cyc  = (const int*)d_in[1];
    const float* adj  = (const float*)d_in[2];
    const float* envf = (const float*)d_in[3];
    const float* Wenv = (const float*)d_in[4];
    const float* benv = (const float*)d_in[5];
    const float* src  = (const float*)d_in[6];
    const float* tgt  = (const float*)d_in[7];
    const float* W    = (const float*)d_in[8];
    const float* bias = (const float*)d_in[9];
    const float* Wres = (const float*)d_in[10];
    const float* bres = (const float*)d_in[11];
    float* out = (float*)d_out;
    char* ws = (char*)d_ws;

    // ws layout (bytes), all 16B-aligned; total ~33.3 MB
    int*   kidx = (int*)(ws + 0);                 // 2,048,000
    float* kval = (float*)(ws + 2048000);         // 2,048,000
    int*   cntw = (int*)(ws + 4096000);           //     8,000
    float* env  = (float*)(ws + 4104000);         //   512,000
    float* supp = (float*)(ws + 4616000);         // 8,192,000
    float* resd = (float*)(ws + 12808000);        // 8,192,000
    float* Tm   = (float*)(ws + 21000000);        // 12,288,000
    int*   pcnt = (int*)(ws + 33288000);          //        96
    int*   plist= (int*)(ws + 33288096);          //     3,072

    hipLaunchKernelGGL(k_env, dim3(NN), dim3(HH), 0, stream, envf, Wenv, benv, env);
    hipLaunchKernelGGL(k_supp_res, dim3((NB * NN + 255) / 256), dim3(256), 0, stream,
                       x, W, Wres, bres, supp, resd);
    hipLaunchKernelGGL(k_tm, dim3((NP * NN * HH / 4 + 255) / 256), dim3(256), 0, stream,
                       tgt, env, Tm);
    hipLaunchKernelGGL(k_sparse, dim3(NN), dim3(256), 0, stream, adj, kidx, kval, cntw);
    hipLaunchKernelGGL(k_periods, dim3(1), dim3(64), 0, stream, cyc, pcnt, plist);
    hipLaunchKernelGGL(k_conv, dim3(NP * NN), dim3(256), 0, stream,
                       src, Tm, env, supp, resd, bias, kidx, kval, cntw, pcnt, plist, out);
}

// Round 2
// 342.821 us; speedup vs baseline: 1.0330x; 1.0330x over previous
//
#include <hip/hip_runtime.h>
#include <hip/hip_bf16.h>
#include <cstdint>

#define NN 2000   // nodes
#define NB 32     // batch
#define DD 32     // d_in == d_out
#define HH 64     // hidden
#define EE 16     // env features
#define NP 24     // periods
#define MAXNZ 256 // per-row nnz storage capacity (mean ~100, sd ~10)
#define NSLOT 20  // register slots per thread in k_conv phase 2 (covers c <= 160)

// ---------------- env = relu(env_features @ W_env + b_env) : [NN, HH] ----------------
__global__ __launch_bounds__(64) void k_env(const float* __restrict__ envf,
                                            const float* __restrict__ Wenv,
                                            const float* __restrict__ benv,
                                            float* __restrict__ env) {
    int n = blockIdx.x, h = threadIdx.x;
    float acc = benv[h];
#pragma unroll
    for (int e = 0; e < EE; ++e) acc = fmaf(envf[n * EE + e], Wenv[e * HH + h], acc);
    env[n * HH + h] = fmaxf(acc, 0.f);
}

// ------- support = x @ W ; residual = relu(x @ Wres + bres) : [NB*NN, DD] each -------
__global__ __launch_bounds__(256) void k_supp_res(const float* __restrict__ x,
                                                  const float* __restrict__ W,
                                                  const float* __restrict__ Wres,
                                                  const float* __restrict__ bres,
                                                  float* __restrict__ supp,
                                                  float* __restrict__ resd) {
    __shared__ float w[DD * DD], wr[DD * DD];
    for (int i = threadIdx.x; i < DD * DD; i += 256) { w[i] = W[i]; wr[i] = Wres[i]; }
    __syncthreads();
    int idx = blockIdx.x * 256 + threadIdx.x;
    if (idx >= NB * NN) return;
    float xv[DD];
    const float4* xr = (const float4*)(x + (size_t)idx * DD);
#pragma unroll
    for (int q = 0; q < DD / 4; ++q) {
        float4 v = xr[q];
        xv[4 * q] = v.x; xv[4 * q + 1] = v.y; xv[4 * q + 2] = v.z; xv[4 * q + 3] = v.w;
    }
    float sa[DD], ra[DD];
#pragma unroll
    for (int m = 0; m < DD; ++m) { sa[m] = 0.f; ra[m] = bres[m]; }
#pragma unroll
    for (int d = 0; d < DD; ++d) {
        float xd = xv[d];
#pragma unroll
        for (int m = 0; m < DD; ++m) {
            sa[m] = fmaf(xd, w[d * DD + m], sa[m]);
            ra[m] = fmaf(xd, wr[d * DD + m], ra[m]);
        }
    }
    float4* so = (float4*)(supp + (size_t)idx * DD);
    float4* ro = (float4*)(resd + (size_t)idx * DD);
#pragma unroll
    for (int q = 0; q < DD / 4; ++q) {
        so[q] = make_float4(sa[4 * q], sa[4 * q + 1], sa[4 * q + 2], sa[4 * q + 3]);
        ro[q] = make_float4(fmaxf(ra[4 * q], 0.f), fmaxf(ra[4 * q + 1], 0.f),
                            fmaxf(ra[4 * q + 2], 0.f), fmaxf(ra[4 * q + 3], 0.f));
    }
}

// ---------------- Tm = tgt_emb + env (broadcast over periods) : [NP, NN, HH] ----------------
__global__ __launch_bounds__(256) void k_tm(const float* __restrict__ tgt,
                                            const float* __restrict__ env,
                                            float* __restrict__ Tm) {
    int i = blockIdx.x * 256 + threadIdx.x;          // float4 index
    if (i >= NP * NN * HH / 4) return;
    int hq = i & (HH / 4 - 1);                       // 0..15
    int pk = i >> 4;                                 // p*NN + k
    int k = pk % NN;
    const float4* t4 = (const float4*)tgt;
    const float4* e4 = (const float4*)env;
    float4 tv = t4[i], ev = e4[k * (HH / 4) + hq];
    ((float4*)Tm)[i] = make_float4(tv.x + ev.x, tv.y + ev.y, tv.z + ev.z, tv.w + ev.w);
}

// ---------------- compact adj rows: kidx/kval lists + counts ----------------
__global__ __launch_bounds__(256) void k_sparse(const float* __restrict__ adj,
                                                int* __restrict__ kidx,
                                                float* __restrict__ kval,
                                                int* __restrict__ cnt) {
    __shared__ int c;
    if (threadIdx.x == 0) c = 0;
    __syncthreads();
    int n = blockIdx.x;
    for (int k = threadIdx.x; k < NN; k += 256) {
        float v = adj[(size_t)n * NN + k];
        if (v > 0.f) {
            int p = atomicAdd(&c, 1);
            if (p < MAXNZ) { kidx[n * MAXNZ + p] = k; kval[n * MAXNZ + p] = v; }
        }
    }
    __syncthreads();
    if (threadIdx.x == 0) cnt[n] = min(c, MAXNZ);
}

// ---------------- period -> batch lists ----------------
__global__ __launch_bounds__(64) void k_periods(const int* __restrict__ cyc,
                                                int* __restrict__ pcnt,
                                                int* __restrict__ plist) {
    __shared__ int c[NP];
    __shared__ int l[NP * NB];
    int t = threadIdx.x;
    if (t < NP) c[t] = 0;
    for (int i = t; i < NP * NB; i += 64) l[i] = 0;
    __syncthreads();
    if (t < NB) {
        int p = cyc[t] % NP; if (p < 0) p += NP;
        int s = atomicAdd(&c[p], 1);
        l[p * NB + s] = t;
    }
    __syncthreads();
    if (t < NP) pcnt[t] = c[t];
    for (int i = t; i < NP * NB; i += 64) plist[i] = l[i];
}

// ---------------- main: per (p, n): sparse A row -> conv -> epilogue ----------------
__global__ __launch_bounds__(256) void k_conv(const float* __restrict__ src,   // [NP,NN,HH]
                                              const float* __restrict__ Tm,    // [NP,NN,HH]
                                              const float* __restrict__ env,   // [NN,HH]
                                              const float* __restrict__ supp,  // [NB,NN,DD]
                                              const float* __restrict__ resd,  // [NB,NN,DD]
                                              const float* __restrict__ bias,  // [DD]
                                              const int* __restrict__ kidx,
                                              const float* __restrict__ kval,
                                              const int* __restrict__ cnt,
                                              const int* __restrict__ pcnt,
                                              const int* __restrict__ plist,
                                              float* __restrict__ out) {
    int bi = blockIdx.x;
    int p = bi / NN;
    int n = bi - p * NN;
    int nb = pcnt[p];
    if (nb == 0) return;                       // inactive period: nothing to do
    __shared__ float S[HH];
    __shared__ float avals[MAXNZ];
    __shared__ int kks[MAXNZ];
    __shared__ float part[128];                // 4 waves x 32 outputs
    int t = threadIdx.x;
    if (t < HH) S[t] = src[((size_t)p * NN + n) * HH + t] + env[n * HH + t];
    int c = cnt[n];
    __syncthreads();
    if (t < c) {                               // one thread per nonzero of row n
        int k = kidx[n * MAXNZ + t];
        const float4* tr = (const float4*)(Tm + ((size_t)p * NN + k) * HH);
        float acc = 0.f;
#pragma unroll
        for (int q = 0; q < HH / 4; ++q) {
            float4 tv = tr[q];
            acc = fmaf(tv.x, S[4 * q], acc);
            acc = fmaf(tv.y, S[4 * q + 1], acc);
            acc = fmaf(tv.z, S[4 * q + 2], acc);
            acc = fmaf(tv.w, S[4 * q + 3], acc);
        }
        avals[t] = fmaxf(acc, 0.f) * kval[n * MAXNZ + t];
        kks[t] = k;
    }
    __syncthreads();

    int m = t & 31, g = t >> 5;                // 8 j-groups x 32 outputs
    int wv = t >> 6;                           // wave id 0..3

    // Preload this thread's j-list into REGISTERS (static indices via full
    // unroll -> no scratch). NSLOT*8 = 160 >= any realistic row count; a
    // dynamic tail loop below guards c > 160 at zero cost when untaken.
    int jk[NSLOT]; float ja[NSLOT];
#pragma unroll
    for (int u = 0; u < NSLOT; ++u) {
        int j = g + (u << 3);
        bool v = j < c;
        int jj = v ? j : 0;
        jk[u] = kks[jj];
        ja[u] = v ? avals[jj] : 0.f;
    }

    for (int ib = 0; ib < nb; ++ib) {
        int b = plist[p * NB + ib];
        const float* sb = supp + (size_t)b * NN * DD + m;
        float vv[NSLOT];
#pragma unroll
        for (int u = 0; u < NSLOT; ++u) vv[u] = sb[(size_t)jk[u] * DD];  // 20 independent loads
        float acc = 0.f;
#pragma unroll
        for (int u = 0; u < NSLOT; ++u) acc = fmaf(ja[u], vv[u], acc);
        for (int j = NSLOT * 8 + g; j < c; j += 8)                       // tail (normally empty)
            acc = fmaf(avals[j], sb[(size_t)kks[j] * DD], acc);
        acc += __shfl_xor(acc, 32);            // combine the two 32-groups in each wave
        if ((t & 63) < 32) part[wv * 32 + m] = acc;
        __syncthreads();
        if (t < DD) {
            float s = bias[t] + part[t] + part[32 + t] + part[64 + t] + part[96 + t];
            size_t o = ((size_t)b * NN + n) * DD + t;
            out[o] = fmaxf(s + resd[o], 0.f);
        }
        __syncthreads();                       // part[] reused next batch
    }
}

extern "C" void kernel_launch(void* const* d_in, const int* in_sizes, int n_in,
                              void* d_out, int out_size, void* d_ws, size_t ws_size,
                              hipStream_t stream) {
    const float* x    = (const float*)d_in[0];
    const int*   cyc  = (const int*)d_in[1];
    const float* adj  = (const float*)d_in[2];
    const float* envf = (const float*)d_in[3];
    const float* Wenv = (const float*)d_in[4];
    const float* benv = (const float*)d_in[5];
    const float* src  = (const float*)d_in[6];
    const float* tgt  = (const float*)d_in[7];
    const float* W    = (const float*)d_in[8];
    const float* bias = (const float*)d_in[9];
    const float* Wres = (const float*)d_in[10];
    const float* bres = (const float*)d_in[11];
    float* out = (float*)d_out;
    char* ws = (char*)d_ws;

    // ws layout (bytes), all 16B-aligned; total ~33.3 MB
    int*   kidx = (int*)(ws + 0);                 // 2,048,000
    float* kval = (float*)(ws + 2048000);         // 2,048,000
    int*   cntw = (int*)(ws + 4096000);           //     8,000
    float* env  = (float*)(ws + 4104000);         //   512,000
    float* supp = (float*)(ws + 4616000);         // 8,192,000
    float* resd = (float*)(ws + 12808000);        // 8,192,000
    float* Tm   = (float*)(ws + 21000000);        // 12,288,000
    int*   pcnt = (int*)(ws + 33288000);          //        96
    int*   plist= (int*)(ws + 33288096);          //     3,072

    hipLaunchKernelGGL(k_env, dim3(NN), dim3(HH), 0, stream, envf, Wenv, benv, env);
    hipLaunchKernelGGL(k_supp_res, dim3((NB * NN + 255) / 256), dim3(256), 0, stream,
                       x, W, Wres, bres, supp, resd);
    hipLaunchKernelGGL(k_tm, dim3((NP * NN * HH / 4 + 255) / 256), dim3(256), 0, stream,
                       tgt, env, Tm);
    hipLaunchKernelGGL(k_sparse, dim3(NN), dim3(256), 0, stream, adj, kidx, kval, cntw);
    hipLaunchKernelGGL(k_periods, dim3(1), dim3(64), 0, stream, cyc, pcnt, plist);
    hipLaunchKernelGGL(k_conv, dim3(NP * NN), dim3(256), 0, stream,
                       src, Tm, env, supp, resd, bias, kidx, kval, cntw, pcnt, plist, out);
}